// Round 1
// baseline (351.574 us; speedup 1.0000x reference)
//
#include <hip/hip_runtime.h>

#define N_SAMP  1024
#define IN_F    512
#define OUT_F   512
#define N_HEADS 32
#define N_SPLITS 4
#define KC      128          // k-chunk staged in LDS
#define XPAD    132          // 128 + 4: keeps float4 stores 16B-aligned, breaks bank aliasing

// Grouped pass. Each block = (group g, 64-column tile). Builds the list of
// samples whose (head [,split]) matches g, stages their X rows in LDS, and
// streams the group's weight tile from global once.
//   DELTA=false: g = head, out = acc + bias   (plain store; sole writer)
//   DELTA=true : g = head*4+split, out += 0.1*acc (RMW; sole writer, after base)
template <int CH, int J, bool DELTA>
__global__ __launch_bounds__(256) void lms_kernel(
    const float* __restrict__ X, const int* __restrict__ head_ix,
    const int* __restrict__ split_ix, const float* __restrict__ Wt,
    const float* __restrict__ bias, float* __restrict__ out)
{
    const int g   = blockIdx.y;
    const int c0  = blockIdx.x * 64;
    const int tid = threadIdx.x;

    __shared__ int   list[N_SAMP];
    __shared__ int   cnt;
    __shared__ float Xc[CH][XPAD];

    if (tid == 0) cnt = 0;
    __syncthreads();

    if (DELTA) {
        const int h = g >> 2, sp = g & 3;
        for (int i = tid; i < N_SAMP; i += 256)
            if (head_ix[i] == h && split_ix[i] == sp) {
                int p = atomicAdd(&cnt, 1); list[p] = i;
            }
    } else {
        for (int i = tid; i < N_SAMP; i += 256)
            if (head_ix[i] == g) {
                int p = atomicAdd(&cnt, 1); list[p] = i;
            }
    }
    __syncthreads();

    const int total = cnt;
    if (total == 0) return;

    const float* Wg = Wt + (size_t)g * IN_F * OUT_F;
    const int srow = tid >> 4;            // sample slot 0..15
    const int col  = c0 + (tid & 15) * 4; // 4 consecutive columns per thread

    float4 bv;
    if (!DELTA) bv = *(const float4*)(bias + (size_t)g * OUT_F + col);

    for (int s0 = 0; s0 < total; s0 += CH) {
        const int nc = min(total - s0, CH);

        float4 acc[J];
#pragma unroll
        for (int j = 0; j < J; ++j) acc[j] = make_float4(0.f, 0.f, 0.f, 0.f);

        for (int k0 = 0; k0 < IN_F; k0 += KC) {
            // Stage Xc[CH][KC]; zero-fill rows >= nc so the inner loop is
            // predication-free.
            for (int i = tid; i < CH * (KC / 4); i += 256) {
                const int r = i >> 5, q = i & 31;
                float4 v = make_float4(0.f, 0.f, 0.f, 0.f);
                if (r < nc)
                    v = *(const float4*)(X + (size_t)list[s0 + r] * IN_F + k0 + q * 4);
                *(float4*)(&Xc[r][q * 4]) = v;
            }
            __syncthreads();

#pragma unroll 4
            for (int kk = 0; kk < KC; ++kk) {
                const float4 w =
                    *(const float4*)(Wg + (size_t)(k0 + kk) * OUT_F + col);
#pragma unroll
                for (int j = 0; j < J; ++j) {
                    const float xv = Xc[srow + 16 * j][kk];  // LDS broadcast, bank-free
                    acc[j].x += xv * w.x;
                    acc[j].y += xv * w.y;
                    acc[j].z += xv * w.z;
                    acc[j].w += xv * w.w;
                }
            }
            __syncthreads();
        }

#pragma unroll
        for (int j = 0; j < J; ++j) {
            const int si = srow + 16 * j;
            if (si < nc) {
                float* op = out + (size_t)list[s0 + si] * OUT_F + col;
                float4 r;
                if (DELTA) {
                    const float4 cur = *(const float4*)op;
                    r = make_float4(cur.x + 0.1f * acc[j].x,
                                    cur.y + 0.1f * acc[j].y,
                                    cur.z + 0.1f * acc[j].z,
                                    cur.w + 0.1f * acc[j].w);
                } else {
                    r = make_float4(acc[j].x + bv.x, acc[j].y + bv.y,
                                    acc[j].z + bv.z, acc[j].w + bv.w);
                }
                *(float4*)op = r;
            }
        }
    }
}

extern "C" void kernel_launch(void* const* d_in, const int* in_sizes, int n_in,
                              void* d_out, int out_size, void* d_ws, size_t ws_size,
                              hipStream_t stream) {
    const float* X        = (const float*)d_in[0];
    const int*   head_ix  = (const int*)d_in[1];
    const int*   split_ix = (const int*)d_in[2];
    const float* W        = (const float*)d_in[3];
    const float* D        = (const float*)d_in[4];
    const float* bias     = (const float*)d_in[5];
    float*       out      = (float*)d_out;

    // Base pass: 32 heads x 8 col-tiles, up to 64 samples/chunk, 4 slots/thread.
    dim3 gb(OUT_F / 64, N_HEADS);
    lms_kernel<64, 4, false><<<gb, 256, 0, stream>>>(X, head_ix, split_ix, W, bias, out);

    // Delta pass: 128 combos x 8 col-tiles, up to 32 samples/chunk, 2 slots/thread.
    dim3 gd(OUT_F / 64, N_HEADS * N_SPLITS);
    lms_kernel<32, 2, true><<<gd, 256, 0, stream>>>(X, head_ix, split_ix, D, bias, out);
}

// Round 2
// 349.330 us; speedup vs baseline: 1.0064x; 1.0064x over previous
//
#include <hip/hip_runtime.h>

#define N_SAMP   1024
#define IN_F     512
#define OUT_F    512
#define N_HEADS  32
#define N_SPLITS 4
#define DELTA_SCALE 0.1f

// Grouped gather-GEMV. Block = (group g, 64-col tile). Builds the sample list
// for g, stages X rows in LDS (zero-filled tail), then streams the group's
// weight tile with an explicitly double-buffered U-deep batch of float4 loads
// (the R1 kernel was latency-bound at 18% VALU / 8% HBM: only 4 loads in
// flight per thread).
//   DELTA=false: g = head,        out = acc + bias      (sole writer)
//   DELTA=true : g = head*4+split, out += 0.1 * acc     (RMW after base pass)
// J slots of 16 => SLOTS sample rows per chunk. Base J=3 (48 covers ~32±6/head),
// delta J=1 (16 covers ~8±3/combo) -- right-sizing removes the 2-4x zero-slot
// FMA waste from R1.
template <int J, int KC, int U, bool DELTA, int MINW>
__global__ __launch_bounds__(256, MINW) void lms_kernel(
    const float* __restrict__ X, const int* __restrict__ head_ix,
    const int* __restrict__ split_ix, const float* __restrict__ Wt,
    const float* __restrict__ bias, float* __restrict__ out)
{
    constexpr int SLOTS = 16 * J;
    constexpr int XP    = KC + 4;   // keeps float4 16B alignment (KC%4==0), breaks stride
    constexpr int QW    = KC / 4;
    constexpr int NB    = KC / U;

    const int g   = blockIdx.y;
    const int c0  = blockIdx.x * 64;
    const int tid = threadIdx.x;

    __shared__ int   list[N_SAMP];
    __shared__ int   cnt;
    __shared__ float Xc[SLOTS][XP];

    if (tid == 0) cnt = 0;
    __syncthreads();

    if (DELTA) {
        const int h = g >> 2, sp = g & 3;
        for (int i = tid; i < N_SAMP; i += 256)
            if (head_ix[i] == h && split_ix[i] == sp) {
                int p = atomicAdd(&cnt, 1); list[p] = i;
            }
    } else {
        for (int i = tid; i < N_SAMP; i += 256)
            if (head_ix[i] == g) { int p = atomicAdd(&cnt, 1); list[p] = i; }
    }
    __syncthreads();
    const int total = cnt;
    if (total == 0) return;

    const float* Wg = Wt + (size_t)g * (IN_F * OUT_F);
    const int sb  = tid >> 4;             // sample slot base 0..15
    const int col = c0 + (tid & 15) * 4;  // 4 consecutive cols per thread

    float4 bv;
    if (!DELTA) bv = *(const float4*)(bias + (size_t)g * OUT_F + col);

    for (int s0 = 0; s0 < total; s0 += SLOTS) {
        const int nc = min(total - s0, SLOTS);

        float4 acc[J];
#pragma unroll
        for (int j = 0; j < J; ++j) acc[j] = make_float4(0.f, 0.f, 0.f, 0.f);

        for (int k0 = 0; k0 < IN_F; k0 += KC) {
            // Stage Xc[SLOTS][KC], zero-filled past nc (predication-free inner loop).
            for (int i = tid; i < SLOTS * QW; i += 256) {
                const int r = i / QW, q = i - r * QW;
                float4 v = make_float4(0.f, 0.f, 0.f, 0.f);
                if (r < nc)
                    v = *(const float4*)(X + (size_t)list[s0 + r] * IN_F + k0 + q * 4);
                *(float4*)(&Xc[r][q * 4]) = v;
            }
            __syncthreads();

            const float* wp = Wg + (size_t)k0 * OUT_F + col;

            // Double-buffered weight batches: U rows of float4 in flight while
            // FMAing the previous batch.
            float4 wcur[U];
#pragma unroll
            for (int u = 0; u < U; ++u)
                wcur[u] = *(const float4*)(wp + (size_t)u * OUT_F);

            for (int b = 0; b < NB; ++b) {
                float4 wnxt[U];
                const bool more = (b + 1 < NB);
                if (more) {
                    const float* wn = wp + (size_t)(b + 1) * U * OUT_F;
#pragma unroll
                    for (int u = 0; u < U; ++u)
                        wnxt[u] = *(const float4*)(wn + (size_t)u * OUT_F);
                }
                // X fragment: U consecutive k per slot, vector LDS reads (broadcast
                // across the 16 lanes sharing a slot -- bank-conflict-free).
                float xr[J][U];
#pragma unroll
                for (int j = 0; j < J; ++j) {
                    const float* xp = &Xc[sb + 16 * j][b * U];
#pragma unroll
                    for (int uu = 0; uu < U; uu += 4) {
                        const float4 xv = *(const float4*)(xp + uu);
                        xr[j][uu + 0] = xv.x; xr[j][uu + 1] = xv.y;
                        xr[j][uu + 2] = xv.z; xr[j][uu + 3] = xv.w;
                    }
                }
#pragma unroll
                for (int u = 0; u < U; ++u)
#pragma unroll
                    for (int j = 0; j < J; ++j) {
                        acc[j].x += xr[j][u] * wcur[u].x;
                        acc[j].y += xr[j][u] * wcur[u].y;
                        acc[j].z += xr[j][u] * wcur[u].z;
                        acc[j].w += xr[j][u] * wcur[u].w;
                    }
                if (more) {
#pragma unroll
                    for (int u = 0; u < U; ++u) wcur[u] = wnxt[u];
                }
            }
            __syncthreads();
        }

#pragma unroll
        for (int j = 0; j < J; ++j) {
            const int si = sb + 16 * j;
            if (si < nc) {
                float* op = out + (size_t)list[s0 + si] * OUT_F + col;
                float4 r;
                if (DELTA) {
                    const float4 cur = *(const float4*)op;
                    r = make_float4(cur.x + DELTA_SCALE * acc[j].x,
                                    cur.y + DELTA_SCALE * acc[j].y,
                                    cur.z + DELTA_SCALE * acc[j].z,
                                    cur.w + DELTA_SCALE * acc[j].w);
                } else {
                    r = make_float4(acc[j].x + bv.x, acc[j].y + bv.y,
                                    acc[j].z + bv.z, acc[j].w + bv.w);
                }
                *(float4*)op = r;
            }
        }
    }
}

extern "C" void kernel_launch(void* const* d_in, const int* in_sizes, int n_in,
                              void* d_out, int out_size, void* d_ws, size_t ws_size,
                              hipStream_t stream) {
    const float* X        = (const float*)d_in[0];
    const int*   head_ix  = (const int*)d_in[1];
    const int*   split_ix = (const int*)d_in[2];
    const float* W        = (const float*)d_in[3];
    const float* D        = (const float*)d_in[4];
    const float* bias     = (const float*)d_in[5];
    float*       out      = (float*)d_out;

    // Base: 32 heads x 8 col-tiles. 48 slots/chunk, KC=256 (Xc 49.9 KB), U=8
    // (8 KB in flight/wave; 1 block/CU so VGPRs are free -- MINW=1).
    dim3 gb(OUT_F / 64, N_HEADS);
    lms_kernel<3, 256, 8, false, 1><<<gb, 256, 0, stream>>>(
        X, head_ix, split_ix, W, bias, out);

    // Delta: 128 combos x 8 col-tiles = 1024 blocks (4/CU). 16 slots, KC=512
    // (whole X rows staged once, no inner barriers; Xc 33 KB => 4 blocks/CU),
    // U=4 keeps VGPR under the 4-waves/SIMD cap (launch_bounds 256,4).
    dim3 gd(OUT_F / 64, N_HEADS * N_SPLITS);
    lms_kernel<1, 512, 4, true, 4><<<gd, 256, 0, stream>>>(
        X, head_ix, split_ix, D, bias, out);
}